// Round 6
// baseline (680.123 us; speedup 1.0000x reference)
//
#include <hip/hip_runtime.h>

// ---------------------------------------------------------------------------
// IDynamicDWConv pipeline, fp32 end-to-end.
// R6: conv@64x64 was LDS-instruction-bound (per wave-ci: 9 ds_read_b32 +
// 9 ds_read_b128 ~ 160 LDS cyc vs 72 VALU cyc -> ~34 us/conv just in LDS
// issue). New conv64s: thread = 4px x 4oc (x reads b128+b64/row amortized
// over 4 px; w b128 over 16 outputs -> ~4x fewer LDS cycles/output).
// Occupancy kept via K-split x4 (16 ci/block, 512 blocks, 2/CU) writing
// fp32 partials; combine (sum4 + bias + lrelu/res) FUSED into the consumer's
// staging; residual-chain values materialized via side-writes (ocg==0).
// Final combine fused into maxpool. Column-per-thread staging: conflict-free
// ds_write_b32 + coalesced global. XCD-grouping: b&7 = tile-group so one
// tile's 64 blocks share one XCD L2 (partial re-reads stay local).
// S=32 chain (R4 kernels), conv1x1, dynconv unchanged.
// ---------------------------------------------------------------------------

__global__ __launch_bounds__(256) void avgpool4_k(const float* __restrict__ x,
                                                  float* __restrict__ y) {
    int idx = blockIdx.x * 256 + threadIdx.x;      // 2*64*64*64 = 524288
    int wo = idx & 63;
    int ho = (idx >> 6) & 63;
    int cz = idx >> 12;                            // n*64+c, 0..127
    const float* base = x + ((long)cz * 256 + ho * 4) * 256 + wo * 4;
    float s = 0.f;
#pragma unroll
    for (int r = 0; r < 4; ++r) {
        float4 v = *(const float4*)(base + r * 256);
        s += v.x + v.y + v.z + v.w;
    }
    y[idx] = s * 0.0625f;
}

// --------------------- conv 3x3 @64, K-split x4, 4px x 4oc -----------------
// Block: 256 thr; tile 32x32 px; thread = 4 w-px x 4 oc (16 acc).
// b (0..511): tg = b&7 -> (n, 32x32 tile) [one tile-group per XCD];
// slot = b>>3: ocg = slot&15 (4 oc), ks = slot>>4 (16-ci K-slice).
// Staging: column-per-thread (ci=t/34, col j=t%34), zero-pad OOB; optional
// COMB mode: v = sum of 4 partials + bias[ch], opt lrelu, opt +res, opt
// side-write of v (the materialized resblock output).
__global__ __launch_bounds__(256) void conv64s_k(
    const float* __restrict__ in0, long pstride,   // pstride>0 => COMB of 4
    const float* __restrict__ sbias, int slrelu,
    const float* __restrict__ sres,
    float* __restrict__ sidew,
    const float* __restrict__ wgt,
    float* __restrict__ outp) {
    __shared__ __align__(16) float s_x[8 * 34 * 36];   // 39168 B
    __shared__ __align__(16) float s_w[16 * 9 * 4];    // 2304 B
    const int tid = threadIdx.x;
    const int b = blockIdx.x;
    const int tg = b & 7;
    const int slot = b >> 3;
    const int n = tg >> 2;
    const int tile = tg & 3;
    const int tx0 = (tile & 1) * 32, ty0 = (tile >> 1) * 32;
    const int ocg = slot & 15, ks = slot >> 4;
    const int oc0 = ocg * 4;

    // Stage weights for (4 oc) x (16 ci of this ks) x 9 taps.
    for (int i = tid; i < 576; i += 256) {
        int k = i / 144;
        int rem = i - k * 144;
        int ci = rem / 9;
        int tap = rem - ci * 9;
        s_w[(ci * 9 + tap) * 4 + k] =
            wgt[(oc0 + k) * 576 + (ks * 16 + ci) * 9 + tap];
    }

    // Staging tasks: 8 ci x 34 cols = 272; thread tid does task tid,
    // threads 0..15 also task 256+tid.
    const int ntask = (tid < 16) ? 2 : 1;
    int t_ci[2], t_j[2];
    t_ci[0] = tid / 34;  t_j[0] = tid - t_ci[0] * 34;
    t_ci[1] = (256 + tid) / 34; t_j[1] = (256 + tid) - t_ci[1] * 34;

    const int tx = tid & 7;            // w strip
    const int ty = tid >> 3;           // 0..31 tile row
    const int px0 = tx * 4;

    float acc[4][4];
#pragma unroll
    for (int k = 0; k < 4; ++k)
#pragma unroll
        for (int p = 0; p < 4; ++p) acc[k][p] = 0.f;

    for (int cc = 0; cc < 2; ++cc) {
        if (cc) __syncthreads();       // compute(0) done before restage
        // ---- stage 8 ci (channels ks*16 + cc*8 + ci) ----
        for (int t = 0; t < ntask; ++t) {
            const int ci = t_ci[t], j = t_j[t];
            const int ch = ks * 16 + cc * 8 + ci;
            const int gcol = tx0 + j - 1;
            const bool colin = (unsigned)gcol < 64u;
            const long chbase = (long)(n * 64 + ch) * 4096;
            float bch = 0.f;
            if (pstride && colin) bch = sbias[ch];
            float* sp = &s_x[(ci * 34) * 36 + j];
#pragma unroll 2
            for (int r = 0; r < 34; ++r) {
                const int grow = ty0 + r - 1;
                float v = 0.f;
                if (colin && (unsigned)grow < 64u) {
                    const long off = chbase + grow * 64 + gcol;
                    if (pstride) {
                        v = in0[off] + in0[off + pstride] +
                            in0[off + 2 * pstride] + in0[off + 3 * pstride] + bch;
                        if (slrelu) v = v > 0.f ? v : 0.1f * v;
                        if (sres) v += sres[off];
                        if (sidew && ocg == 0) sidew[off] = v;
                    } else {
                        v = in0[off];
                    }
                }
                sp[r * 36] = v;
            }
        }
        __syncthreads();
        // ---- compute 8 ci ----
#pragma unroll 2
        for (int ci = 0; ci < 8; ++ci) {
            float xr[3][6];
#pragma unroll
            for (int r3 = 0; r3 < 3; ++r3) {
                const float* rp = &s_x[(ci * 34 + ty + r3) * 36 + px0];
                float4 a = *(const float4*)rp;
                float2 e = *(const float2*)(rp + 4);
                xr[r3][0] = a.x; xr[r3][1] = a.y; xr[r3][2] = a.z;
                xr[r3][3] = a.w; xr[r3][4] = e.x; xr[r3][5] = e.y;
            }
            const int cif = cc * 8 + ci;
#pragma unroll
            for (int dh = 0; dh < 3; ++dh)
#pragma unroll
                for (int dw = 0; dw < 3; ++dw) {
                    float4 wv = *(const float4*)&s_w[(cif * 9 + dh * 3 + dw) * 4];
#pragma unroll
                    for (int p = 0; p < 4; ++p) {
                        float xv = xr[dh][p + dw];
                        acc[0][p] += xv * wv.x;
                        acc[1][p] += xv * wv.y;
                        acc[2][p] += xv * wv.z;
                        acc[3][p] += xv * wv.w;
                    }
                }
        }
    }

    const int gy = ty0 + ty, gx = tx0 + px0;
#pragma unroll
    for (int k = 0; k < 4; ++k) {
        float4 v;
        v.x = acc[k][0]; v.y = acc[k][1]; v.z = acc[k][2]; v.w = acc[k][3];
        long off = (long)ks * 524288 +
                   ((long)(n * 64 + oc0 + k) * 64 + gy) * 64 + gx;
        *(float4*)&outp[off] = v;
    }
}

// maxpool2 fused with final combine: y = sum4(Pb) + bias + res, pool 2x2.
__global__ __launch_bounds__(256) void maxpool_comb_k(
    const float* __restrict__ Pb, const float* __restrict__ bias,
    const float* __restrict__ res, float* __restrict__ P) {
    int idx = blockIdx.x * 256 + threadIdx.x;      // 131072
    int wo = idx & 31;
    int ho = (idx >> 5) & 31;
    int cz = idx >> 10;                            // n*64+c
    float bch = bias[cz & 63];
    float m = -3.4e38f;
#pragma unroll
    for (int dh = 0; dh < 2; ++dh)
#pragma unroll
        for (int dw = 0; dw < 2; ++dw) {
            long off = ((long)cz * 64 + ho * 2 + dh) * 64 + wo * 2 + dw;
            float y = Pb[off] + Pb[off + 524288] + Pb[off + 1048576] +
                      Pb[off + 1572864] + bch + res[off];
            m = fmaxf(m, y);
        }
    P[idx] = m;
}

// ------------------ R4 conv3x3 (kept for S=32 chain) -----------------------
template <int S, int OCB>
__global__ __launch_bounds__(256) void conv3x3_t(
    const float* __restrict__ in, const float* __restrict__ wgt,
    const float* __restrict__ bias, const float* __restrict__ res,
    float* __restrict__ out, int lrelu) {
    __shared__ __align__(16) float s_w[64 * 9 * OCB];
    __shared__ float s_in[16 * 342];               // [ci][18r][19c]
    const int tid = threadIdx.x;
    const int tx = tid & 15;
    const int ty = tid >> 4;
    const int tw = blockIdx.x * 16, th = blockIdx.y * 16;
    const int n = blockIdx.z / (64 / OCB);
    const int oc0 = (blockIdx.z % (64 / OCB)) * OCB;

    for (int idx = tid; idx < OCB * 576; idx += 256) {
        int k = idx / 576;
        int r = idx - k * 576;
        int ci = r / 9;
        int tap = r - ci * 9;
        s_w[(ci * 9 + tap) * OCB + k] = wgt[(long)oc0 * 576 + idx];
    }

    constexpr int NLD = 21;
    int g_off[NLD];
    int l_off[NLD];
    unsigned vmask = 0;
#pragma unroll
    for (int j = 0; j < NLD; ++j) {
        int idx = tid + j * 256;
        int t = idx < 5184 ? idx : 5183;
        int ci = t / 324;
        int rem = t - ci * 324;
        int r = rem / 18;
        int c = rem - r * 18;
        int gh = th + r - 1, gw = tw + c - 1;
        if (idx < 5184 && (unsigned)gh < (unsigned)S && (unsigned)gw < (unsigned)S)
            vmask |= (1u << j);
        int ghc = gh < 0 ? 0 : (gh > S - 1 ? S - 1 : gh);
        int gwc = gw < 0 ? 0 : (gw > S - 1 ? S - 1 : gw);
        g_off[j] = ci * S * S + ghc * S + gwc;
        l_off[j] = ci * 342 + r * 19 + c;
    }

    const float* inb = in + (long)n * 64 * S * S;
    float pf[NLD];
#pragma unroll
    for (int j = 0; j < NLD; ++j) pf[j] = inb[g_off[j]];

    float acc[OCB];
#pragma unroll
    for (int k = 0; k < OCB; ++k) acc[k] = 0.f;

    for (int chunk = 0; chunk < 64; chunk += 16) {
        __syncthreads();
#pragma unroll
        for (int j = 0; j < NLD; ++j) {
            float v = ((vmask >> j) & 1u) ? pf[j] : 0.f;
            if (j < 20 || tid < 64) s_in[l_off[j]] = v;
        }
        __syncthreads();
        if (chunk + 16 < 64) {
            const float* nb = inb + (chunk + 16) * S * S;
#pragma unroll
            for (int j = 0; j < NLD; ++j) pf[j] = nb[g_off[j]];
        }
#pragma unroll 4
        for (int ci = 0; ci < 16; ++ci) {
            const float* sp = &s_in[ci * 342 + ty * 19 + tx];
            float xw[9];
#pragma unroll
            for (int r = 0; r < 3; ++r)
#pragma unroll
                for (int c = 0; c < 3; ++c)
                    xw[r * 3 + c] = sp[r * 19 + c];
            const float* wp = &s_w[(chunk + ci) * 9 * OCB];
#pragma unroll
            for (int t = 0; t < 9; ++t) {
                float xv = xw[t];
                if constexpr (OCB == 4) {
                    float4 wv = *(const float4*)&wp[t * 4];
                    acc[0] += xv * wv.x;
                    acc[1] += xv * wv.y;
                    acc[2] += xv * wv.z;
                    acc[3] += xv * wv.w;
                } else {
                    float2 wv = *(const float2*)&wp[t * 2];
                    acc[0] += xv * wv.x;
                    acc[1] += xv * wv.y;
                }
            }
        }
    }

    const int h = th + ty, w = tw + tx;
#pragma unroll
    for (int k = 0; k < OCB; ++k) {
        int oc = oc0 + k;
        float v = acc[k] + bias[oc];
        if (lrelu) v = v > 0.f ? v : 0.1f * v;
        long off = ((long)(n * 64 + oc) * S + h) * S + w;
        if (res) v += res[off];
        out[off] = v;
    }
}

// 1x1 conv 64 -> 576 at 32x32. Block: 256 px, 8 oc. Weights in LDS.
__global__ __launch_bounds__(256) void conv1x1_k(
    const float* __restrict__ in, const float* __restrict__ w,
    const float* __restrict__ b, float* __restrict__ out) {
    __shared__ float s_in[32 * 256];
    __shared__ __align__(16) float s_w[64 * 8];
    const int tid = threadIdx.x;
    const int p0 = blockIdx.x * 256;
    const int cog = blockIdx.y;
    const int n = blockIdx.z;

    for (int idx = tid; idx < 512; idx += 256) {
        int j = idx >> 6;
        int ci = idx & 63;
        s_w[ci * 8 + j] = w[(long)cog * 512 + idx];
    }

    float acc[8];
#pragma unroll
    for (int i = 0; i < 8; ++i) acc[i] = b[cog * 8 + i];

    float pf[32];
#pragma unroll
    for (int i = 0; i < 32; ++i)
        pf[i] = in[(long)(n * 64 + i) * 1024 + p0 + tid];

    for (int chunk = 0; chunk < 64; chunk += 32) {
        __syncthreads();
#pragma unroll
        for (int i = 0; i < 32; ++i) s_in[i * 256 + tid] = pf[i];
        __syncthreads();
        if (chunk + 32 < 64) {
#pragma unroll
            for (int i = 0; i < 32; ++i)
                pf[i] = in[(long)(n * 64 + chunk + 32 + i) * 1024 + p0 + tid];
        }
#pragma unroll 4
        for (int ci = 0; ci < 32; ++ci) {
            float v = s_in[ci * 256 + tid];
            float4 w0 = *(const float4*)&s_w[(chunk + ci) * 8];
            float4 w1 = *(const float4*)&s_w[(chunk + ci) * 8 + 4];
            acc[0] += v * w0.x; acc[1] += v * w0.y;
            acc[2] += v * w0.z; acc[3] += v * w0.w;
            acc[4] += v * w1.x; acc[5] += v * w1.y;
            acc[6] += v * w1.z; acc[7] += v * w1.w;
        }
    }
#pragma unroll
    for (int oc = 0; oc < 8; ++oc)
        out[(long)(n * 576 + cog * 8 + oc) * 1024 + p0 + tid] = acc[oc];
}

// Fused bilinear x8 upsample + dynamic depthwise 3x3 (replicate pad on x).
__global__ __launch_bounds__(256) void dynconv_k(
    const float* __restrict__ x, const float* __restrict__ wt,
    float* __restrict__ out) {
    __shared__ __align__(16) float s_x[10 * 132];
    const int tid = threadIdx.x;
    const int tx = tid & 31;
    const int ty = tid >> 5;
    const int tw = (blockIdx.x & 1) * 128;
    const int th = (blockIdx.x >> 1) * 8;
    const int cz = blockIdx.y;

    const float* xb = x + (long)cz * 65536;
    for (int idx = tid; idx < 1300; idx += 256) {
        int r = idx / 130;
        int c = idx - r * 130;
        int gh = min(max(th + r - 1, 0), 255);
        int gw = min(max(tw + c - 1, 0), 255);
        s_x[r * 132 + c] = xb[gh * 256 + gw];
    }

    const int h = th + ty;
    const int wbase = tw + tx * 4;

    float src_h = h * 0.125f - 0.4375f;
    int h0 = (int)floorf(src_h);
    float fh = src_h - (float)h0;
    int h0c = min(max(h0, 0), 31), h1c = min(max(h0 + 1, 0), 31);
    float src_w = wbase * 0.125f - 0.4375f;
    int w0 = (int)floorf(src_w);
    float fw0 = src_w - (float)w0;
    int w0c = min(max(w0, 0), 31), w1c = min(max(w0 + 1, 0), 31);

    __syncthreads();

    float vals[3][6];
#pragma unroll
    for (int r = 0; r < 3; ++r) {
        const float* rp = &s_x[(ty + r) * 132 + tx * 4];
        float4 a = *(const float4*)rp;
        float2 b = *(const float2*)(rp + 4);
        vals[r][0] = a.x; vals[r][1] = a.y; vals[r][2] = a.z;
        vals[r][3] = a.w; vals[r][4] = b.x; vals[r][5] = b.y;
    }

    const float* wtb = wt + (long)cz * 9 * 1024;
    float acc[4] = {0.f, 0.f, 0.f, 0.f};
#pragma unroll
    for (int dh = 0; dh < 3; ++dh)
#pragma unroll
        for (int dw = 0; dw < 3; ++dw) {
            const float* p = wtb + (dh * 3 + dw) * 1024;
            float w00 = p[h0c * 32 + w0c], w01 = p[h0c * 32 + w1c];
            float w10 = p[h1c * 32 + w0c], w11 = p[h1c * 32 + w1c];
            float c0 = w00 + fh * (w10 - w00);
            float c1 = w01 + fh * (w11 - w01);
            float d = c1 - c0;
#pragma unroll
            for (int j = 0; j < 4; ++j) {
                float wv = c0 + (fw0 + 0.125f * j) * d;
                acc[j] += vals[dh][j + dw] * wv;
            }
        }

    float4 o;
    o.x = acc[0]; o.y = acc[1]; o.z = acc[2]; o.w = acc[3];
    *(float4*)&out[(long)cz * 65536 + h * 256 + wbase] = o;
}

extern "C" void kernel_launch(void* const* d_in, const int* in_sizes, int n_in,
                              void* d_out, int out_size, void* d_ws, size_t ws_size,
                              hipStream_t stream) {
    const float* x    = (const float*)d_in[0];
    const float* b1w1 = (const float*)d_in[1];
    const float* b1b1 = (const float*)d_in[2];
    const float* b1w2 = (const float*)d_in[3];
    const float* b1b2 = (const float*)d_in[4];
    const float* b2w1 = (const float*)d_in[5];
    const float* b2b1 = (const float*)d_in[6];
    const float* b2w2 = (const float*)d_in[7];
    const float* b2b2 = (const float*)d_in[8];
    const float* tokw = (const float*)d_in[9];
    const float* tokb = (const float*)d_in[10];
    float* out = (float*)d_out;
    float* ws = (float*)d_ws;

    // Buffers (floats):
    float* A  = ws;                 // 524288  [2,64,64,64] avgpool out
    float* Y1 = ws + 524288;        // 524288  resblock outputs (side-written)
    float* Y2 = ws + 1048576;       // 524288
    float* Pa = ws + 1572864;       // 2097152 partials (4 x 524288)
    float* Pb = ws + 3670016;       // 2097152
    float* P  = ws + 5767168;       // 131072  [2,64,32,32]
    float* Q  = ws + 5898240;       // 131072
    float* U  = ws + 6029312;       // 131072
    float* WT = ws + 6160384;       // 1179648 [2,576,32,32]

    const int WSZ = 64 * 64 * 9;
    const long PS = 524288;         // partial ks-stride

    avgpool4_k<<<2048, 256, 0, stream>>>(x, A);

    // rb1: conv1 (plain A) -> Pa; conv2 (comb Pa,b1,lrelu) -> Pb
    conv64s_k<<<512, 256, 0, stream>>>(A,  0,  nullptr,      0, nullptr, nullptr, b1w1 + 0 * WSZ, Pa);
    conv64s_k<<<512, 256, 0, stream>>>(Pa, PS, b1b1 + 0,     1, nullptr, nullptr, b1w2 + 0 * WSZ, Pb);
    // rb2: conv1 (comb Pb,b2,res=A, side-write Y1) -> Pa; conv2 -> Pb
    conv64s_k<<<512, 256, 0, stream>>>(Pb, PS, b1b2 + 0,     0, A,       Y1,      b1w1 + 1 * WSZ, Pa);
    conv64s_k<<<512, 256, 0, stream>>>(Pa, PS, b1b1 + 64,    1, nullptr, nullptr, b1w2 + 1 * WSZ, Pb);
    // rb3: conv1 (comb Pb,b2,res=Y1, side-write Y2) -> Pa; conv2 -> Pb
    conv64s_k<<<512, 256, 0, stream>>>(Pb, PS, b1b2 + 64,    0, Y1,      Y2,      b1w1 + 2 * WSZ, Pa);
    conv64s_k<<<512, 256, 0, stream>>>(Pa, PS, b1b1 + 128,   1, nullptr, nullptr, b1w2 + 2 * WSZ, Pb);

    // maxpool with final combine (sum Pb + b1b2[128..] + Y2)
    maxpool_comb_k<<<512, 256, 0, stream>>>(Pb, b1b2 + 128, Y2, P);

    dim3 g32(2, 2, 64);
    conv3x3_t<32, 2><<<g32, 256, 0, stream>>>(P, b2w1 + 0 * WSZ, b2b1 + 0,   nullptr, U, 1);
    conv3x3_t<32, 2><<<g32, 256, 0, stream>>>(U, b2w2 + 0 * WSZ, b2b2 + 0,   P,       Q, 0);
    conv3x3_t<32, 2><<<g32, 256, 0, stream>>>(Q, b2w1 + 1 * WSZ, b2b1 + 64,  nullptr, U, 1);
    conv3x3_t<32, 2><<<g32, 256, 0, stream>>>(U, b2w2 + 1 * WSZ, b2b2 + 64,  Q,       P, 0);
    conv3x3_t<32, 2><<<g32, 256, 0, stream>>>(P, b2w1 + 2 * WSZ, b2b1 + 128, nullptr, U, 1);
    conv3x3_t<32, 2><<<g32, 256, 0, stream>>>(U, b2w2 + 2 * WSZ, b2b2 + 128, P,       Q, 0);

    conv1x1_k<<<dim3(4, 72, 2), 256, 0, stream>>>(Q, tokw, tokb, WT);

    dynconv_k<<<dim3(64, 128), 256, 0, stream>>>(x, WT, out);
}

// Round 7
// 387.887 us; speedup vs baseline: 1.7534x; 1.7534x over previous
//
#include <hip/hip_runtime.h>

// ---------------------------------------------------------------------------
// IDynamicDWConv pipeline, fp32 end-to-end.
// R7: conv3x3 = R4's proven flat coalesced staging (R6's column staging was
// the regression: 34-deep strided scalar load chain, VALUBusy 9%) + R6's
// 4px x 4oc compute mapping (4x fewer LDS cycles/output than R4: 6 x-reads
// + 9 wave-uniform w-b128 per wave-ci for 1024 outputs). Occupancy held by
// K-split (S=64: 16ci x 4ks = 512 blocks; S=32: 8ci x 8ks = 256 blocks).
// Partial combine moved OUT of staging into trivial float4 kernels
// (sum + bias + lrelu/res); rb3's combine fused into maxpool (R6-verified).
// ---------------------------------------------------------------------------

__global__ __launch_bounds__(256) void avgpool4_k(const float* __restrict__ x,
                                                  float* __restrict__ y) {
    int idx = blockIdx.x * 256 + threadIdx.x;      // 524288
    int wo = idx & 63;
    int ho = (idx >> 6) & 63;
    int cz = idx >> 12;
    const float* base = x + ((long)cz * 256 + ho * 4) * 256 + wo * 4;
    float s = 0.f;
#pragma unroll
    for (int r = 0; r < 4; ++r) {
        float4 v = *(const float4*)(base + r * 256);
        s += v.x + v.y + v.z + v.w;
    }
    y[idx] = s * 0.0625f;
}

// K-split direct 3x3 conv. Block: 256 thr = 16x16 px x 16 oc (4 waves,
// wave-uniform 4 oc). Lane: 4 w-px x 4 oc. CIB input channels per block.
// Partial out: [ks][n][oc][S][S], pstride = 2*64*S*S.
template <int S, int CIB>
__global__ __launch_bounds__(256) void conv3x3s_k(
    const float* __restrict__ in, const float* __restrict__ wgt,
    float* __restrict__ outp) {
    constexpr int KSN = 64 / CIB;
    constexpr int TPS = S / 16;
    constexpr int NT = TPS * TPS;
    constexpr int TOT = CIB * 324;                 // 18x18 halo tile x CIB
    constexpr int NLD = (TOT + 255) / 256;
    constexpr int TAIL = TOT - (NLD - 1) * 256;
    __shared__ float s_in[CIB * 360];              // [ci][18r][20c] aligned
    __shared__ __align__(16) float s_w[CIB * 144]; // [ci][tap][16oc]

    const int tid = threadIdx.x;
    int z = blockIdx.x;
    const int ks = z % KSN; z /= KSN;
    const int ocg = z & 3; z >>= 2;
    const int tile = z % NT;
    const int n = z / NT;
    const int th = (tile / TPS) * 16, tw = (tile % TPS) * 16;
    const int oc0 = ocg * 16;

    // Stage weights: [oc][ci][tap] -> [ci][tap][16oc] (coalesced in rem).
    for (int i = tid; i < CIB * 144; i += 256) {
        int k = i / (CIB * 9);
        int rem = i - k * (CIB * 9);
        s_w[rem * 16 + k] = wgt[(oc0 + k) * 576 + ks * (CIB * 9) + rem];
    }

    // Stage input tile (flat coalesced burst, zero OOB).
    const float* inb = in + ((long)n * 64 + ks * CIB) * (S * S);
#pragma unroll
    for (int j = 0; j < NLD; ++j) {
        int idx = tid + j * 256;
        bool slot = (j < NLD - 1) || (tid < TAIL);
        int t = slot ? idx : 0;
        int ci = t / 324;
        int rem = t - ci * 324;
        int r = rem / 18;
        int c = rem - r * 18;
        int gh = th + r - 1, gw = tw + c - 1;
        float v = 0.f;
        if (slot && (unsigned)gh < (unsigned)S && (unsigned)gw < (unsigned)S)
            v = inb[ci * (S * S) + gh * S + gw];
        if (slot) s_in[ci * 360 + r * 20 + c] = v;
    }
    __syncthreads();

    const int lane = tid & 63;
    const int wid = tid >> 6;                      // wave id -> 4-oc slice
    const int tx4 = (lane & 3) * 4;
    const int ty = lane >> 2;

    float acc[4][4];
#pragma unroll
    for (int k = 0; k < 4; ++k)
#pragma unroll
        for (int p = 0; p < 4; ++p) acc[k][p] = 0.f;

#pragma unroll 2
    for (int ci = 0; ci < CIB; ++ci) {
        float xr[3][6];
#pragma unroll
        for (int r = 0; r < 3; ++r) {
            const float* rp = &s_in[ci * 360 + (ty + r) * 20 + tx4];
            float4 a = *(const float4*)rp;
            float2 b = *(const float2*)(rp + 4);
            xr[r][0] = a.x; xr[r][1] = a.y; xr[r][2] = a.z;
            xr[r][3] = a.w; xr[r][4] = b.x; xr[r][5] = b.y;
        }
#pragma unroll
        for (int dh = 0; dh < 3; ++dh)
#pragma unroll
            for (int dw = 0; dw < 3; ++dw) {
                float4 wv = *(const float4*)&s_w[(ci * 9 + dh * 3 + dw) * 16 + wid * 4];
#pragma unroll
                for (int p = 0; p < 4; ++p) {
                    float xv = xr[dh][p + dw];
                    acc[0][p] += xv * wv.x;
                    acc[1][p] += xv * wv.y;
                    acc[2][p] += xv * wv.z;
                    acc[3][p] += xv * wv.w;
                }
            }
    }

    const int gy = th + ty, gx = tw + tx4;
    const long pstride = (long)2 * 64 * S * S;
#pragma unroll
    for (int k = 0; k < 4; ++k) {
        float4 v;
        v.x = acc[k][0]; v.y = acc[k][1]; v.z = acc[k][2]; v.w = acc[k][3];
        long off = ks * pstride +
                   ((long)(n * 64 + oc0 + wid * 4 + k)) * (S * S) + gy * S + gx;
        *(float4*)&outp[off] = v;
    }
}

// Combine NP partials + bias (+lrelu / +res), float4 per thread.
template <int NP, int SSLOG, bool LRELU, bool RES>
__global__ __launch_bounds__(256) void comb_k(
    const float* __restrict__ P, const float* __restrict__ bias,
    const float* __restrict__ res, float* __restrict__ out) {
    const long pstride = (long)2 * 64 << SSLOG;
    long base = ((long)blockIdx.x * 256 + threadIdx.x) * 4;
    int c = (int)((base >> SSLOG) & 63);
    float4 v = *(const float4*)&P[base];
#pragma unroll
    for (int p = 1; p < NP; ++p) {
        float4 u = *(const float4*)&P[base + p * pstride];
        v.x += u.x; v.y += u.y; v.z += u.z; v.w += u.w;
    }
    float b = bias[c];
    v.x += b; v.y += b; v.z += b; v.w += b;
    if (LRELU) {
        v.x = v.x > 0.f ? v.x : 0.1f * v.x;
        v.y = v.y > 0.f ? v.y : 0.1f * v.y;
        v.z = v.z > 0.f ? v.z : 0.1f * v.z;
        v.w = v.w > 0.f ? v.w : 0.1f * v.w;
    }
    if (RES) {
        float4 r = *(const float4*)&res[base];
        v.x += r.x; v.y += r.y; v.z += r.z; v.w += r.w;
    }
    *(float4*)&out[base] = v;
}

// maxpool2 fused with final combine: y = sum4(P) + bias + res, pool 2x2.
__global__ __launch_bounds__(256) void maxpool_comb_k(
    const float* __restrict__ Pb, const float* __restrict__ bias,
    const float* __restrict__ res, float* __restrict__ P) {
    int idx = blockIdx.x * 256 + threadIdx.x;      // 131072
    int wo = idx & 31;
    int ho = (idx >> 5) & 31;
    int cz = idx >> 10;
    float bch = bias[cz & 63];
    float m = -3.4e38f;
#pragma unroll
    for (int dh = 0; dh < 2; ++dh)
#pragma unroll
        for (int dw = 0; dw < 2; ++dw) {
            long off = ((long)cz * 64 + ho * 2 + dh) * 64 + wo * 2 + dw;
            float y = Pb[off] + Pb[off + 524288] + Pb[off + 1048576] +
                      Pb[off + 1572864] + bch + res[off];
            m = fmaxf(m, y);
        }
    P[idx] = m;
}

// 1x1 conv 64 -> 576 at 32x32. Block: 256 px, 8 oc. Weights in LDS.
__global__ __launch_bounds__(256) void conv1x1_k(
    const float* __restrict__ in, const float* __restrict__ w,
    const float* __restrict__ b, float* __restrict__ out) {
    __shared__ float s_in[32 * 256];
    __shared__ __align__(16) float s_w[64 * 8];
    const int tid = threadIdx.x;
    const int p0 = blockIdx.x * 256;
    const int cog = blockIdx.y;
    const int n = blockIdx.z;

    for (int idx = tid; idx < 512; idx += 256) {
        int j = idx >> 6;
        int ci = idx & 63;
        s_w[ci * 8 + j] = w[(long)cog * 512 + idx];
    }

    float acc[8];
#pragma unroll
    for (int i = 0; i < 8; ++i) acc[i] = b[cog * 8 + i];

    float pf[32];
#pragma unroll
    for (int i = 0; i < 32; ++i)
        pf[i] = in[(long)(n * 64 + i) * 1024 + p0 + tid];

    for (int chunk = 0; chunk < 64; chunk += 32) {
        __syncthreads();
#pragma unroll
        for (int i = 0; i < 32; ++i) s_in[i * 256 + tid] = pf[i];
        __syncthreads();
        if (chunk + 32 < 64) {
#pragma unroll
            for (int i = 0; i < 32; ++i)
                pf[i] = in[(long)(n * 64 + chunk + 32 + i) * 1024 + p0 + tid];
        }
#pragma unroll 4
        for (int ci = 0; ci < 32; ++ci) {
            float v = s_in[ci * 256 + tid];
            float4 w0 = *(const float4*)&s_w[(chunk + ci) * 8];
            float4 w1 = *(const float4*)&s_w[(chunk + ci) * 8 + 4];
            acc[0] += v * w0.x; acc[1] += v * w0.y;
            acc[2] += v * w0.z; acc[3] += v * w0.w;
            acc[4] += v * w1.x; acc[5] += v * w1.y;
            acc[6] += v * w1.z; acc[7] += v * w1.w;
        }
    }
#pragma unroll
    for (int oc = 0; oc < 8; ++oc)
        out[(long)(n * 576 + cog * 8 + oc) * 1024 + p0 + tid] = acc[oc];
}

// Fused bilinear x8 upsample + dynamic depthwise 3x3 (replicate pad on x).
__global__ __launch_bounds__(256) void dynconv_k(
    const float* __restrict__ x, const float* __restrict__ wt,
    float* __restrict__ out) {
    __shared__ __align__(16) float s_x[10 * 132];
    const int tid = threadIdx.x;
    const int tx = tid & 31;
    const int ty = tid >> 5;
    const int tw = (blockIdx.x & 1) * 128;
    const int th = (blockIdx.x >> 1) * 8;
    const int cz = blockIdx.y;

    const float* xb = x + (long)cz * 65536;
    for (int idx = tid; idx < 1300; idx += 256) {
        int r = idx / 130;
        int c = idx - r * 130;
        int gh = min(max(th + r - 1, 0), 255);
        int gw = min(max(tw + c - 1, 0), 255);
        s_x[r * 132 + c] = xb[gh * 256 + gw];
    }

    const int h = th + ty;
    const int wbase = tw + tx * 4;

    float src_h = h * 0.125f - 0.4375f;
    int h0 = (int)floorf(src_h);
    float fh = src_h - (float)h0;
    int h0c = min(max(h0, 0), 31), h1c = min(max(h0 + 1, 0), 31);
    float src_w = wbase * 0.125f - 0.4375f;
    int w0 = (int)floorf(src_w);
    float fw0 = src_w - (float)w0;
    int w0c = min(max(w0, 0), 31), w1c = min(max(w0 + 1, 0), 31);

    __syncthreads();

    float vals[3][6];
#pragma unroll
    for (int r = 0; r < 3; ++r) {
        const float* rp = &s_x[(ty + r) * 132 + tx * 4];
        float4 a = *(const float4*)rp;
        float2 b = *(const float2*)(rp + 4);
        vals[r][0] = a.x; vals[r][1] = a.y; vals[r][2] = a.z;
        vals[r][3] = a.w; vals[r][4] = b.x; vals[r][5] = b.y;
    }

    const float* wtb = wt + (long)cz * 9 * 1024;
    float acc[4] = {0.f, 0.f, 0.f, 0.f};
#pragma unroll
    for (int dh = 0; dh < 3; ++dh)
#pragma unroll
        for (int dw = 0; dw < 3; ++dw) {
            const float* p = wtb + (dh * 3 + dw) * 1024;
            float w00 = p[h0c * 32 + w0c], w01 = p[h0c * 32 + w1c];
            float w10 = p[h1c * 32 + w0c], w11 = p[h1c * 32 + w1c];
            float c0 = w00 + fh * (w10 - w00);
            float c1 = w01 + fh * (w11 - w01);
            float d = c1 - c0;
#pragma unroll
            for (int j = 0; j < 4; ++j) {
                float wv = c0 + (fw0 + 0.125f * j) * d;
                acc[j] += vals[dh][j + dw] * wv;
            }
        }

    float4 o;
    o.x = acc[0]; o.y = acc[1]; o.z = acc[2]; o.w = acc[3];
    *(float4*)&out[(long)cz * 65536 + h * 256 + wbase] = o;
}

extern "C" void kernel_launch(void* const* d_in, const int* in_sizes, int n_in,
                              void* d_out, int out_size, void* d_ws, size_t ws_size,
                              hipStream_t stream) {
    const float* x    = (const float*)d_in[0];
    const float* b1w1 = (const float*)d_in[1];
    const float* b1b1 = (const float*)d_in[2];
    const float* b1w2 = (const float*)d_in[3];
    const float* b1b2 = (const float*)d_in[4];
    const float* b2w1 = (const float*)d_in[5];
    const float* b2b1 = (const float*)d_in[6];
    const float* b2w2 = (const float*)d_in[7];
    const float* b2b2 = (const float*)d_in[8];
    const float* tokw = (const float*)d_in[9];
    const float* tokb = (const float*)d_in[10];
    float* out = (float*)d_out;
    float* ws = (float*)d_ws;

    // Buffers (floats):
    float* X0 = ws;                 // 524288 [2,64,64,64]
    float* X1 = ws + 524288;        // 524288
    float* T  = ws + 1048576;       // 524288
    float* P  = ws + 1572864;       // 2097152 partials (max 4x524288 / 8x131072)
    float* Pm = ws + 3670016;       // 131072 [2,64,32,32]
    float* Q  = ws + 3801088;       // 131072
    float* U  = ws + 3932160;       // 131072
    float* WT = ws + 4063232;       // 1179648 [2,576,32,32]

    const int WSZ = 64 * 64 * 9;

    avgpool4_k<<<2048, 256, 0, stream>>>(x, X0);

    // ---- S=64 resblocks: conv -> comb(lrelu) -> conv -> comb(res) ----
    conv3x3s_k<64, 16><<<512, 256, 0, stream>>>(X0, b1w1 + 0 * WSZ, P);
    comb_k<4, 12, true,  false><<<512, 256, 0, stream>>>(P, b1b1 + 0, nullptr, T);
    conv3x3s_k<64, 16><<<512, 256, 0, stream>>>(T, b1w2 + 0 * WSZ, P);
    comb_k<4, 12, false, true ><<<512, 256, 0, stream>>>(P, b1b2 + 0, X0, X1);

    conv3x3s_k<64, 16><<<512, 256, 0, stream>>>(X1, b1w1 + 1 * WSZ, P);
    comb_k<4, 12, true,  false><<<512, 256, 0, stream>>>(P, b1b1 + 64, nullptr, T);
    conv3x3s_k<64, 16><<<512, 256, 0, stream>>>(T, b1w2 + 1 * WSZ, P);
    comb_k<4, 12, false, true ><<<512, 256, 0, stream>>>(P, b1b2 + 64, X1, X0);

    conv3x3s_k<64, 16><<<512, 256, 0, stream>>>(X0, b1w1 + 2 * WSZ, P);
    comb_k<4, 12, true,  false><<<512, 256, 0, stream>>>(P, b1b1 + 128, nullptr, T);
    conv3x3s_k<64, 16><<<512, 256, 0, stream>>>(T, b1w2 + 2 * WSZ, P);
    maxpool_comb_k<<<512, 256, 0, stream>>>(P, b1b2 + 128, X0, Pm);

    // ---- S=32 resblocks ----
    conv3x3s_k<32, 8><<<256, 256, 0, stream>>>(Pm, b2w1 + 0 * WSZ, P);
    comb_k<8, 10, true,  false><<<128, 256, 0, stream>>>(P, b2b1 + 0, nullptr, U);
    conv3x3s_k<32, 8><<<256, 256, 0, stream>>>(U, b2w2 + 0 * WSZ, P);
    comb_k<8, 10, false, true ><<<128, 256, 0, stream>>>(P, b2b2 + 0, Pm, Q);

    conv3x3s_k<32, 8><<<256, 256, 0, stream>>>(Q, b2w1 + 1 * WSZ, P);
    comb_k<8, 10, true,  false><<<128, 256, 0, stream>>>(P, b2b1 + 64, nullptr, U);
    conv3x3s_k<32, 8><<<256, 256, 0, stream>>>(U, b2w2 + 1 * WSZ, P);
    comb_k<8, 10, false, true ><<<128, 256, 0, stream>>>(P, b2b2 + 64, Q, Pm);

    conv3x3s_k<32, 8><<<256, 256, 0, stream>>>(Pm, b2w1 + 2 * WSZ, P);
    comb_k<8, 10, true,  false><<<128, 256, 0, stream>>>(P, b2b1 + 128, nullptr, U);
    conv3x3s_k<32, 8><<<256, 256, 0, stream>>>(U, b2w2 + 2 * WSZ, P);
    comb_k<8, 10, false, true ><<<128, 256, 0, stream>>>(P, b2b2 + 128, Pm, Q);

    conv1x1_k<<<dim3(4, 72, 2), 256, 0, stream>>>(Q, tokw, tokb, WT);

    dynconv_k<<<dim3(64, 128), 256, 0, stream>>>(x, WT, out);
}

// Round 8
// 369.307 us; speedup vs baseline: 1.8416x; 1.0503x over previous
//
#include <hip/hip_runtime.h>

// ---------------------------------------------------------------------------
// IDynamicDWConv pipeline, fp32 end-to-end.
// R8: (1) conv3x3 re-mapped for fewer LDS instrs/output: lane = PXL px x 4 oc
//     (conv64: PXL=8, tile 32x16, CIB=8, ks=8; conv32: PXL=4, tile 16x16,
//     CIB=4, ks=16; both 512 blocks = 2/CU, 8 waves/CU). Per wave-ci LDS
//     drops from 162cyc/1024out (R7) to 204cyc/2048out -> ~5.4us/conv64.
// (2) dynconv: wt bilinear window (9 taps x 3 rows x 18 cols, block-uniform)
//     staged in LDS with clamp-duplicated edges -> corner pairs are float2
//     LDS reads (2/tap) instead of 4 scattered global loads; ~HBM-floor.
// (3) combs stay separate float4 kernels (R7-verified; fusing into staging
//     multiplies partial traffic by ocg x halo — analyzed, rejected).
// ---------------------------------------------------------------------------

__global__ __launch_bounds__(256) void avgpool4_k(const float* __restrict__ x,
                                                  float* __restrict__ y) {
    int idx = blockIdx.x * 256 + threadIdx.x;      // 524288
    int wo = idx & 63;
    int ho = (idx >> 6) & 63;
    int cz = idx >> 12;
    const float* base = x + ((long)cz * 256 + ho * 4) * 256 + wo * 4;
    float s = 0.f;
#pragma unroll
    for (int r = 0; r < 4; ++r) {
        float4 v = *(const float4*)(base + r * 256);
        s += v.x + v.y + v.z + v.w;
    }
    y[idx] = s * 0.0625f;
}

// K-split direct 3x3 conv (zero-pad SAME). Block: 256 thr = 4 waves; each
// wave = full TWxTH tile for a 4-oc slice; lane = PXL w-px x 4 oc.
// Partials out: [ks][n][oc][S][S].
template <int S, int CIB, int TW, int PXL>
__global__ __launch_bounds__(256) void conv3x3w_k(
    const float* __restrict__ in, const float* __restrict__ wgt,
    float* __restrict__ outp) {
    constexpr int KSN = 64 / CIB;
    constexpr int TH = 16;
    constexpr int NTW = S / TW, NTH = S / TH;
    constexpr int NT = NTW * NTH;
    constexpr int HW = TW + 2;
    constexpr int SROW = TW + 4;
    constexpr int TOT = CIB * 18 * HW;
    constexpr int NLD = (TOT + 255) / 256;
    constexpr int TAIL = TOT - (NLD - 1) * 256;
    __shared__ float s_in[CIB * 18 * SROW];
    __shared__ __align__(16) float s_w[CIB * 144];   // [ci][tap][16oc]

    const int tid = threadIdx.x;
    int z = blockIdx.x;
    const int ks = z % KSN; z /= KSN;
    const int ocg = z & 3; z >>= 2;
    const int tile = z % NT;
    const int n = z / NT;
    const int th0 = (tile / NTW) * TH, tw0 = (tile % NTW) * TW;
    const int oc0 = ocg * 16;

    // Weights: [oc][ci][tap] -> [ci][tap][16oc].
    for (int i = tid; i < CIB * 144; i += 256) {
        int k = i / (CIB * 9);
        int rem = i - k * (CIB * 9);
        s_w[rem * 16 + k] = wgt[(oc0 + k) * 576 + ks * (CIB * 9) + rem];
    }

    // Input tile staging: flat coalesced burst, zero OOB.
    const float* inb = in + ((long)n * 64 + ks * CIB) * (S * S);
#pragma unroll
    for (int j = 0; j < NLD; ++j) {
        int idx = tid + j * 256;
        bool slot = (j < NLD - 1) || (tid < TAIL);
        int t = slot ? idx : 0;
        int ci = t / (18 * HW);
        int rem = t - ci * (18 * HW);
        int r = rem / HW;
        int c = rem - r * HW;
        int gh = th0 + r - 1, gw = tw0 + c - 1;
        float v = 0.f;
        if (slot && (unsigned)gh < (unsigned)S && (unsigned)gw < (unsigned)S)
            v = inb[ci * (S * S) + gh * S + gw];
        if (slot) s_in[ci * (18 * SROW) + r * SROW + c] = v;
    }
    __syncthreads();

    const int lane = tid & 63;
    const int wid = tid >> 6;                      // 4-oc slice
    const int lx = lane & 3;                       // 4 strips across TW
    const int ly = lane >> 2;                      // 0..15 row
    const int px0 = lx * PXL;

    float acc[4][PXL];
#pragma unroll
    for (int k = 0; k < 4; ++k)
#pragma unroll
        for (int p = 0; p < PXL; ++p) acc[k][p] = 0.f;

#pragma unroll
    for (int ci = 0; ci < CIB; ++ci) {
        float xr[3][PXL + 2];
#pragma unroll
        for (int r = 0; r < 3; ++r) {
            const float* rp = &s_in[ci * (18 * SROW) + (ly + r) * SROW + px0];
#pragma unroll
            for (int q = 0; q < PXL / 4; ++q) {
                float4 a = *(const float4*)(rp + q * 4);
                xr[r][q * 4 + 0] = a.x; xr[r][q * 4 + 1] = a.y;
                xr[r][q * 4 + 2] = a.z; xr[r][q * 4 + 3] = a.w;
            }
            float2 b = *(const float2*)(rp + PXL);
            xr[r][PXL] = b.x; xr[r][PXL + 1] = b.y;
        }
#pragma unroll
        for (int dh = 0; dh < 3; ++dh)
#pragma unroll
            for (int dw = 0; dw < 3; ++dw) {
                float4 wv = *(const float4*)&s_w[(ci * 9 + dh * 3 + dw) * 16 + wid * 4];
#pragma unroll
                for (int p = 0; p < PXL; ++p) {
                    float xv = xr[dh][p + dw];
                    acc[0][p] += xv * wv.x;
                    acc[1][p] += xv * wv.y;
                    acc[2][p] += xv * wv.z;
                    acc[3][p] += xv * wv.w;
                }
            }
    }

    const int gy = th0 + ly, gx = tw0 + px0;
    const long pstride = (long)2 * 64 * S * S;
#pragma unroll
    for (int k = 0; k < 4; ++k) {
        long off = ks * pstride +
                   ((long)(n * 64 + oc0 + wid * 4 + k)) * (S * S) + gy * S + gx;
#pragma unroll
        for (int q = 0; q < PXL / 4; ++q) {
            float4 v;
            v.x = acc[k][q * 4 + 0]; v.y = acc[k][q * 4 + 1];
            v.z = acc[k][q * 4 + 2]; v.w = acc[k][q * 4 + 3];
            *(float4*)&outp[off + q * 4] = v;
        }
    }
}

// Combine NP partials + bias (+lrelu / +res), float4 per thread.
template <int NP, int SSLOG, bool LRELU, bool RES>
__global__ __launch_bounds__(256) void comb_k(
    const float* __restrict__ P, const float* __restrict__ bias,
    const float* __restrict__ res, float* __restrict__ out) {
    const long pstride = (long)2 * 64 << SSLOG;
    long base = ((long)blockIdx.x * 256 + threadIdx.x) * 4;
    int c = (int)((base >> SSLOG) & 63);
    float4 v = *(const float4*)&P[base];
#pragma unroll
    for (int p = 1; p < NP; ++p) {
        float4 u = *(const float4*)&P[base + p * pstride];
        v.x += u.x; v.y += u.y; v.z += u.z; v.w += u.w;
    }
    float b = bias[c];
    v.x += b; v.y += b; v.z += b; v.w += b;
    if (LRELU) {
        v.x = v.x > 0.f ? v.x : 0.1f * v.x;
        v.y = v.y > 0.f ? v.y : 0.1f * v.y;
        v.z = v.z > 0.f ? v.z : 0.1f * v.z;
        v.w = v.w > 0.f ? v.w : 0.1f * v.w;
    }
    if (RES) {
        float4 r = *(const float4*)&res[base];
        v.x += r.x; v.y += r.y; v.z += r.z; v.w += r.w;
    }
    *(float4*)&out[base] = v;
}

// maxpool2 fused with final combine: y = sumNP(P) + bias + res, pool 2x2.
template <int NP>
__global__ __launch_bounds__(256) void maxpool_comb_k(
    const float* __restrict__ Pb, const float* __restrict__ bias,
    const float* __restrict__ res, float* __restrict__ P) {
    int idx = blockIdx.x * 256 + threadIdx.x;      // 131072
    int wo = idx & 31;
    int ho = (idx >> 5) & 31;
    int cz = idx >> 10;
    float bch = bias[cz & 63];
    float m = -3.4e38f;
#pragma unroll
    for (int dh = 0; dh < 2; ++dh)
#pragma unroll
        for (int dw = 0; dw < 2; ++dw) {
            long off = ((long)cz * 64 + ho * 2 + dh) * 64 + wo * 2 + dw;
            float y = bch + res[off];
#pragma unroll
            for (int p = 0; p < NP; ++p) y += Pb[off + (long)p * 524288];
            m = fmaxf(m, y);
        }
    P[idx] = m;
}

// 1x1 conv 64 -> 576 at 32x32. Block: 256 px, 8 oc. Weights in LDS.
__global__ __launch_bounds__(256) void conv1x1_k(
    const float* __restrict__ in, const float* __restrict__ w,
    const float* __restrict__ b, float* __restrict__ out) {
    __shared__ float s_in[32 * 256];
    __shared__ __align__(16) float s_w[64 * 8];
    const int tid = threadIdx.x;
    const int p0 = blockIdx.x * 256;
    const int cog = blockIdx.y;
    const int n = blockIdx.z;

    for (int idx = tid; idx < 512; idx += 256) {
        int j = idx >> 6;
        int ci = idx & 63;
        s_w[ci * 8 + j] = w[(long)cog * 512 + idx];
    }

    float acc[8];
#pragma unroll
    for (int i = 0; i < 8; ++i) acc[i] = b[cog * 8 + i];

    float pf[32];
#pragma unroll
    for (int i = 0; i < 32; ++i)
        pf[i] = in[(long)(n * 64 + i) * 1024 + p0 + tid];

    for (int chunk = 0; chunk < 64; chunk += 32) {
        __syncthreads();
#pragma unroll
        for (int i = 0; i < 32; ++i) s_in[i * 256 + tid] = pf[i];
        __syncthreads();
        if (chunk + 32 < 64) {
#pragma unroll
            for (int i = 0; i < 32; ++i)
                pf[i] = in[(long)(n * 64 + chunk + 32 + i) * 1024 + p0 + tid];
        }
#pragma unroll 4
        for (int ci = 0; ci < 32; ++ci) {
            float v = s_in[ci * 256 + tid];
            float4 w0 = *(const float4*)&s_w[(chunk + ci) * 8];
            float4 w1 = *(const float4*)&s_w[(chunk + ci) * 8 + 4];
            acc[0] += v * w0.x; acc[1] += v * w0.y;
            acc[2] += v * w0.z; acc[3] += v * w0.w;
            acc[4] += v * w1.x; acc[5] += v * w1.y;
            acc[6] += v * w1.z; acc[7] += v * w1.w;
        }
    }
#pragma unroll
    for (int oc = 0; oc < 8; ++oc)
        out[(long)(n * 576 + cog * 8 + oc) * 1024 + p0 + tid] = acc[oc];
}

// Fused bilinear x8 upsample + dynamic depthwise 3x3 (replicate pad on x).
// wt bilinear window staged in LDS: taps x 3 rows x 18 cols (block-uniform
// h0min=th/8-1, w0min=tw/8-1), clamp-duplicated so (j,j+1)/(r,r+1) always
// valid -> per tap 2 float2 LDS reads.
__global__ __launch_bounds__(256) void dynconv_k(
    const float* __restrict__ x, const float* __restrict__ wt,
    float* __restrict__ out) {
    __shared__ __align__(16) float s_x[10 * 132];
    __shared__ float s_wt[9 * 60];                 // [tap][3r][20c], 0..17 used
    const int tid = threadIdx.x;
    const int tx = tid & 31;
    const int ty = tid >> 5;
    const int tw = (blockIdx.x & 1) * 128;
    const int th = (blockIdx.x >> 1) * 8;
    const int cz = blockIdx.y;

    const float* xb = x + (long)cz * 65536;
    for (int idx = tid; idx < 1300; idx += 256) {
        int r = idx / 130;
        int c = idx - r * 130;
        int gh = min(max(th + r - 1, 0), 255);
        int gw = min(max(tw + c - 1, 0), 255);
        s_x[r * 132 + c] = xb[gh * 256 + gw];
    }

    const int h0min = th / 8 - 1;                  // th multiple of 8
    const int w0min = tw / 8 - 1;
    const float* wtb = wt + (long)cz * 9 * 1024;
    for (int i = tid; i < 540; i += 256) {
        int tap = i / 60;
        int rem = i - tap * 60;
        int r = rem / 20;
        int c = rem - r * 20;
        if (c < 18) {
            int gr = min(max(h0min + r, 0), 31);
            int gc = min(max(w0min + c, 0), 31);
            s_wt[i] = wtb[tap * 1024 + gr * 32 + gc];
        }
    }

    const int h = th + ty;
    const int wbase = tw + tx * 4;
    float src_h = h * 0.125f - 0.4375f;
    int h0 = (int)floorf(src_h);
    float fh = src_h - (float)h0;
    int r0 = h0 - h0min;                           // 0 or 1
    float src_w = wbase * 0.125f - 0.4375f;
    int w0 = (int)floorf(src_w);
    float fw0 = src_w - (float)w0;
    int j = w0 - w0min;                            // 0..16

    __syncthreads();

    float vals[3][6];
#pragma unroll
    for (int r = 0; r < 3; ++r) {
        const float* rp = &s_x[(ty + r) * 132 + tx * 4];
        float4 a = *(const float4*)rp;
        float2 b = *(const float2*)(rp + 4);
        vals[r][0] = a.x; vals[r][1] = a.y; vals[r][2] = a.z;
        vals[r][3] = a.w; vals[r][4] = b.x; vals[r][5] = b.y;
    }

    float acc[4] = {0.f, 0.f, 0.f, 0.f};
#pragma unroll
    for (int dh = 0; dh < 3; ++dh)
#pragma unroll
        for (int dw = 0; dw < 3; ++dw) {
            const float* p = &s_wt[(dh * 3 + dw) * 60 + r0 * 20 + j];
            float t0 = p[0], t1 = p[1];
            float b0 = p[20], b1 = p[21];
            float c0 = t0 + fh * (b0 - t0);
            float c1 = t1 + fh * (b1 - t1);
            float d = c1 - c0;
#pragma unroll
            for (int jj = 0; jj < 4; ++jj) {
                float wv = c0 + (fw0 + 0.125f * jj) * d;
                acc[jj] += vals[dh][jj + dw] * wv;
            }
        }

    float4 o;
    o.x = acc[0]; o.y = acc[1]; o.z = acc[2]; o.w = acc[3];
    *(float4*)&out[(long)cz * 65536 + h * 256 + wbase] = o;
}

extern "C" void kernel_launch(void* const* d_in, const int* in_sizes, int n_in,
                              void* d_out, int out_size, void* d_ws, size_t ws_size,
                              hipStream_t stream) {
    const float* x    = (const float*)d_in[0];
    const float* b1w1 = (const float*)d_in[1];
    const float* b1b1 = (const float*)d_in[2];
    const float* b1w2 = (const float*)d_in[3];
    const float* b1b2 = (const float*)d_in[4];
    const float* b2w1 = (const float*)d_in[5];
    const float* b2b1 = (const float*)d_in[6];
    const float* b2w2 = (const float*)d_in[7];
    const float* b2b2 = (const float*)d_in[8];
    const float* tokw = (const float*)d_in[9];
    const float* tokb = (const float*)d_in[10];
    float* out = (float*)d_out;
    float* ws = (float*)d_ws;

    // Buffers (floats):
    float* X0 = ws;                 // 524288 [2,64,64,64]
    float* X1 = ws + 524288;        // 524288
    float* T  = ws + 1048576;       // 524288
    float* P  = ws + 1572864;       // 4194304 partials (8x524288 / 16x131072)
    float* Pm = ws + 5767168;       // 131072 [2,64,32,32]
    float* Q  = ws + 5898240;       // 131072
    float* U  = ws + 6029312;       // 131072
    float* WT = ws + 6160384;       // 1179648 [2,576,32,32]

    const int WSZ = 64 * 64 * 9;

    avgpool4_k<<<2048, 256, 0, stream>>>(x, X0);

    // ---- S=64 resblocks (conv: CIB=8, ks=8, tile 32x16, lane 8px x 4oc) ----
    conv3x3w_k<64, 8, 32, 8><<<512, 256, 0, stream>>>(X0, b1w1 + 0 * WSZ, P);
    comb_k<8, 12, true,  false><<<512, 256, 0, stream>>>(P, b1b1 + 0, nullptr, T);
    conv3x3w_k<64, 8, 32, 8><<<512, 256, 0, stream>>>(T, b1w2 + 0 * WSZ, P);
    comb_k<8, 12, false, true ><<<512, 256, 0, stream>>>(P, b1b2 + 0, X0, X1);

    conv3x3w_k<64, 8, 32, 8><<<512, 256, 0, stream>>>(X1, b1w1 + 1 * WSZ, P);
    comb_k<8, 12, true,  false><<<512, 256, 0, stream>>>(P, b1b1 + 64, nullptr, T);
    conv3x3w_k<64, 8, 32, 8><<<512, 256, 0, stream>>>(T, b1w2 + 1 * WSZ, P);
    comb_k<8, 12, false, true ><<<512, 256, 0, stream>>>(P, b1b2 + 64, X1, X0);

    conv3x3w_k<64, 8, 32, 8><<<512, 256, 0, stream>>>(X0, b1w1 + 2 * WSZ, P);
    comb_k<8, 12, true,  false><<<512, 256, 0, stream>>>(P, b1b1 + 128, nullptr, T);
    conv3x3w_k<64, 8, 32, 8><<<512, 256, 0, stream>>>(T, b1w2 + 2 * WSZ, P);
    maxpool_comb_k<8><<<512, 256, 0, stream>>>(P, b1b2 + 128, X0, Pm);

    // ---- S=32 resblocks (conv: CIB=4, ks=16, tile 16x16, lane 4px x 4oc) ----
    conv3x3w_k<32, 4, 16, 4><<<512, 256, 0, stream>>>(Pm, b2w1 + 0 * WSZ, P);
    comb_k<16, 10, true,  false><<<128, 256, 0, stream>>>(P, b2b1 + 0, nullptr, U);
    conv3x3w_k<32, 4, 16, 4><<<512, 256, 0, stream>>>(U, b2w2 + 0 * WSZ, P);
    comb_k<16, 10, false, true ><<<128, 256, 0, stream>>>(P, b2b2 + 0, Pm, Q);

    conv3x3w_k<32, 4, 16, 4><<<512, 256, 0, stream>>>(Q, b2w1 + 1 * WSZ, P);
    comb_k<16, 10, true,  false><<<128, 256, 0, stream>>>(P, b2b1 + 64, nullptr, U);
    conv3x3w_k<32, 4, 16, 4><<<512, 256, 0, stream>>>(U, b2w2 + 1 * WSZ, P);
    comb_k<16, 10, false, true ><<<128, 256, 0, stream>>>(P, b2b2 + 64, Q, Pm);

    conv3x3w_k<32, 4, 16, 4><<<512, 256, 0, stream>>>(Pm, b2w1 + 2 * WSZ, P);
    comb_k<16, 10, true,  false><<<128, 256, 0, stream>>>(P, b2b1 + 128, nullptr, U);
    conv3x3w_k<32, 4, 16, 4><<<512, 256, 0, stream>>>(U, b2w2 + 2 * WSZ, P);
    comb_k<16, 10, false, true ><<<128, 256, 0, stream>>>(P, b2b2 + 128, Pm, Q);

    conv1x1_k<<<dim3(4, 72, 2), 256, 0, stream>>>(Q, tokw, tokb, WT);

    dynconv_k<<<dim3(64, 128), 256, 0, stream>>>(x, WT, out);
}